// Round 5
// baseline (898.353 us; speedup 1.0000x reference)
//
#include <hip/hip_runtime.h>

#define S_LEN 1024
#define BATCH 4096
#define NIN 64
#define NHID 128
#define BT 16      // batch rows per block

typedef __attribute__((ext_vector_type(8))) short bf16x8;
typedef __attribute__((ext_vector_type(4))) float f32x4;

// LDS map (bytes):
//   [0, 8192)      h double-buffer: buf b at b<<12, k-tile kk at kk<<10, lane*16
//   [8192, 40960)  xp ring, 4 slots: slot s at XP_BASE+(s<<13), n-tile w at w<<10, lane*16
#define XP_BASE 8192

__device__ __forceinline__ unsigned short f2bf(float f) {
    union { float f; unsigned u; } v; v.f = f;
    unsigned r = v.u + 0x7FFFu + ((v.u >> 16) & 1u);   // RNE
    return (unsigned short)(r >> 16);
}
__device__ __forceinline__ float bf2f(unsigned short h) {
    union { float f; unsigned u; } v; v.u = ((unsigned)h) << 16;
    return v.f;
}
__device__ __forceinline__ unsigned cvt_pk(float lo, float hi) {
    unsigned r;
    asm("v_cvt_pk_bf16_f32 %0, %1, %2" : "=v"(r) : "v"(lo), "v"(hi));
    return r;
}
__device__ __forceinline__ float tanh_fast(float z) {
    float u = __builtin_amdgcn_exp2f(z * 2.885390081777927f);
    return (u - 1.0f) * __builtin_amdgcn_rcpf(u + 1.0f);
}
// Barrier WITHOUT vmcnt(0) drain (producers' global loads stay in flight)
__device__ __forceinline__ void lds_barrier() {
    asm volatile("s_waitcnt lgkmcnt(0)\n\ts_barrier" ::: "memory");
}

__global__ __launch_bounds__(1024, 4)
void rnn_kernel(const float* __restrict__ x,
                const float* __restrict__ W_ih,
                const float* __restrict__ b_ih,
                const float* __restrict__ W_hh,
                const float* __restrict__ b_hh,
                float* __restrict__ out)
{
    __shared__ __align__(16) char lds[40960];

    const int tid  = threadIdx.x;
    const int w    = tid >> 6;    // 0..7 compute (h rows 16w..+15), 8..15 producer
    const int lane = tid & 63;
    const int col  = lane & 15;   // batch index within tile
    const int kg   = lane >> 4;   // k-group 0..3

    const int bb0 = blockIdx.x * BT;

    // zero both h buffers (h_0 = 0): 8192 B = 2048 ints, 1024 threads
    for (int i = tid; i < 2048; i += 1024) ((int*)lds)[i] = 0;

    const int rd_off = lane << 4;
    const int wr_off = ((w >> 1) << 10) + ((2 * (w & 1) + (kg >> 1)) << 8)
                     + (col << 4) + ((kg & 1) << 3);
    const f32x4 z4 = {0.f, 0.f, 0.f, 0.f};

    if (w < 8) {
        // ================= COMPUTE WAVES =================
        bf16x8 whh_h[4], whh_l[4];
        const int nrow = 16 * w + col;
        #pragma unroll
        for (int kk = 0; kk < 4; ++kk) {
            const float* p = W_hh + nrow * NHID + kk * 32 + kg * 8;
            #pragma unroll
            for (int j = 0; j < 8; ++j) {
                float f = p[j];
                unsigned short hi = f2bf(f);
                whh_h[kk][j] = (short)hi;
                whh_l[kk][j] = (short)f2bf(f - bf2f(hi));
            }
        }
        __syncthreads();   // rendezvous with producer prologue

        auto cstep = [&](int t, int slot, bool last) {
            const char* rbase = lds + ((t & 1) << 12) + rd_off;
            bf16x8 hf0 = *(const bf16x8*)(rbase);
            bf16x8 hf1 = *(const bf16x8*)(rbase + 1024);
            bf16x8 hf2 = *(const bf16x8*)(rbase + 2048);
            bf16x8 hf3 = *(const bf16x8*)(rbase + 3072);
            f32x4 xp = *(const f32x4*)(lds + XP_BASE + (slot << 13)
                                       + (w << 10) + rd_off);
            f32x4 cA = xp, cB = z4, cC = z4, cD = z4;
            cA = __builtin_amdgcn_mfma_f32_16x16x32_bf16(whh_h[0], hf0, cA, 0, 0, 0);
            cC = __builtin_amdgcn_mfma_f32_16x16x32_bf16(whh_l[0], hf0, cC, 0, 0, 0);
            cB = __builtin_amdgcn_mfma_f32_16x16x32_bf16(whh_h[2], hf2, cB, 0, 0, 0);
            cD = __builtin_amdgcn_mfma_f32_16x16x32_bf16(whh_l[2], hf2, cD, 0, 0, 0);
            cA = __builtin_amdgcn_mfma_f32_16x16x32_bf16(whh_h[1], hf1, cA, 0, 0, 0);
            cC = __builtin_amdgcn_mfma_f32_16x16x32_bf16(whh_l[1], hf1, cC, 0, 0, 0);
            cB = __builtin_amdgcn_mfma_f32_16x16x32_bf16(whh_h[3], hf3, cB, 0, 0, 0);
            cD = __builtin_amdgcn_mfma_f32_16x16x32_bf16(whh_l[3], hf3, cD, 0, 0, 0);
            f32x4 acc = (cA + cB) + (cC + cD);

            float t0 = tanh_fast(acc[0]);
            float t1 = tanh_fast(acc[1]);
            float t2 = tanh_fast(acc[2]);
            float t3 = tanh_fast(acc[3]);

            if (last) {
                f32x4 o = {t0, t1, t2, t3};
                *(f32x4*)(out + ((size_t)bb0 + col) * NHID + 16 * w + 4 * kg) = o;
            } else {
                uint2 hb;
                hb.x = cvt_pk(t0, t1);
                hb.y = cvt_pk(t2, t3);
                *(uint2*)(lds + (((t + 1) & 1) << 12) + wr_off) = hb;
            }
            lds_barrier();
        };

        for (int t = 0; t < S_LEN - 4; t += 4) {
            cstep(t + 0, 0, false);
            cstep(t + 1, 1, false);
            cstep(t + 2, 2, false);
            cstep(t + 3, 3, false);
        }
        cstep(S_LEN - 4, 0, false);
        cstep(S_LEN - 3, 1, false);
        cstep(S_LEN - 2, 2, false);
        cstep(S_LEN - 1, 3, true);
    } else {
        // ================= PRODUCER WAVES =================
        const int p = w - 8;     // xp n-tile: rows 16p..16p+15
        bf16x8 wih_h[2];
        const int nrow = 16 * p + col;
        #pragma unroll
        for (int kk = 0; kk < 2; ++kk) {
            const float* q = W_ih + nrow * NIN + kk * 32 + kg * 8;
            #pragma unroll
            for (int j = 0; j < 8; ++j) wih_h[kk][j] = (short)f2bf(q[j]);
        }
        f32x4 biasv;
        {
            f32x4 bi = *(const f32x4*)(b_ih + 16 * p + 4 * kg);
            f32x4 bh = *(const f32x4*)(b_hh + 16 * p + 4 * kg);
            biasv = bi + bh;
        }
        const float* xlane = x + ((size_t)bb0 + col) * NIN + kg * 8;
        char* ring = lds + XP_BASE + (p << 10) + rd_off;

        auto loadStage = [&](f32x4& v0, f32x4& v1, f32x4& v2, f32x4& v3, int t) {
            if (t < S_LEN) {
                const float* q = xlane + (size_t)t * (BATCH * NIN);
                v0 = *(const f32x4*)(q);      v1 = *(const f32x4*)(q + 4);
                v2 = *(const f32x4*)(q + 32); v3 = *(const f32x4*)(q + 36);
            }
        };
        auto xpWrite = [&](const f32x4& v0, const f32x4& v1,
                           const f32x4& v2, const f32x4& v3, int slot) {
            union { bf16x8 v; unsigned u[4]; } a, b;
            a.u[0] = cvt_pk(v0[0], v0[1]); a.u[1] = cvt_pk(v0[2], v0[3]);
            a.u[2] = cvt_pk(v1[0], v1[1]); a.u[3] = cvt_pk(v1[2], v1[3]);
            b.u[0] = cvt_pk(v2[0], v2[1]); b.u[1] = cvt_pk(v2[2], v2[3]);
            b.u[2] = cvt_pk(v3[0], v3[1]); b.u[3] = cvt_pk(v3[2], v3[3]);
            f32x4 xp = biasv;
            xp = __builtin_amdgcn_mfma_f32_16x16x32_bf16(wih_h[0], a.v, xp, 0, 0, 0);
            xp = __builtin_amdgcn_mfma_f32_16x16x32_bf16(wih_h[1], b.v, xp, 0, 0, 0);
            *(f32x4*)(ring + (slot << 13)) = xp;
        };

        // prologue: prime ring slots 0..2 with xp(0..2); prefetch x(3), x(4)
        f32x4 A0, A1, A2, A3, B0, B1, B2, B3;
        {
            f32x4 v0, v1, v2, v3;
            loadStage(v0, v1, v2, v3, 0); xpWrite(v0, v1, v2, v3, 0);
            loadStage(v0, v1, v2, v3, 1); xpWrite(v0, v1, v2, v3, 1);
            loadStage(v0, v1, v2, v3, 2); xpWrite(v0, v1, v2, v3, 2);
        }
        loadStage(A0, A1, A2, A3, 3);
        loadStage(B0, B1, B2, B3, 4);
        __syncthreads();   // rendezvous with compute waves

        // steady state: at step t produce xp(t+3) (from stage holding x(t+3)),
        // refill stage with x(t+5). Barrier count matches compute: S_LEN total.
        auto pstep = [&](int t, f32x4& s0, f32x4& s1, f32x4& s2, f32x4& s3) {
            if (t + 3 < S_LEN) xpWrite(s0, s1, s2, s3, (t + 3) & 3);
            loadStage(s0, s1, s2, s3, t + 5);
            lds_barrier();
        };
        for (int t = 0; t < S_LEN; t += 2) {
            pstep(t,     A0, A1, A2, A3);
            pstep(t + 1, B0, B1, B2, B3);
        }
    }
}

extern "C" void kernel_launch(void* const* d_in, const int* in_sizes, int n_in,
                              void* d_out, int out_size, void* d_ws, size_t ws_size,
                              hipStream_t stream) {
    const float* x    = (const float*)d_in[0];
    const float* W_ih = (const float*)d_in[1];
    const float* b_ih = (const float*)d_in[2];
    const float* W_hh = (const float*)d_in[3];
    const float* b_hh = (const float*)d_in[4];
    float* out = (float*)d_out;

    dim3 grid(BATCH / BT);
    dim3 block(1024);
    rnn_kernel<<<grid, block, 0, stream>>>(x, W_ih, b_ih, W_hh, b_hh, out);
}

// Round 6
// 752.580 us; speedup vs baseline: 1.1937x; 1.1937x over previous
//
#include <hip/hip_runtime.h>

#define S_LEN 1024
#define BATCH 4096
#define NIN 64
#define NHID 128
#define BT 16      // batch rows per block (= per compute wave)

typedef __attribute__((ext_vector_type(8))) short bf16x8;
typedef __attribute__((ext_vector_type(4))) float f32x4;

__device__ __forceinline__ unsigned cvt_pk(float lo, float hi) {
    unsigned r;
    asm("v_cvt_pk_bf16_f32 %0, %1, %2" : "=v"(r) : "v"(lo), "v"(hi));
    return r;
}
__device__ __forceinline__ float tanh_fast(float z) {
    float u = __builtin_amdgcn_exp2f(z * 2.885390081777927f);
    return (u - 1.0f) * __builtin_amdgcn_rcpf(u + 1.0f);
}
// barrier without vmcnt drain (producer's global x loads stay in flight)
__device__ __forceinline__ void lds_barrier() {
    asm volatile("s_waitcnt lgkmcnt(0)\n\ts_barrier" ::: "memory");
}

#define MFMA __builtin_amdgcn_mfma_f32_16x16x32_bf16

// LDS: xp ring, 8 slots x 8KB. slot s at s<<13; n-tile tt at tt<<10; lane*16.
// All LDS traffic is lane-contiguous b128 (conflict-free).
//
// Permuted-k trick: B-slot (kk, kg, j) [phys k = 32kk+8kg+j] carries logical
// hidden index m(k) = 32kk + 16*(j>>2) + 4kg + (j&3). This makes the next-step
// B-fragment equal to a cvt_pk repack of the SAME LANE's C-registers:
//   B[kk] = pack(acc[2kk][0..3], acc[2kk+1][0..3])   — no cross-lane movement.
// W_hh is loaded column-permuted to match; xp, x, and out stay natural.

__global__ __launch_bounds__(128, 1)
void rnn_kernel(const float* __restrict__ x,
                const float* __restrict__ W_ih,
                const float* __restrict__ b_ih,
                const float* __restrict__ W_hh,
                const float* __restrict__ b_hh,
                float* __restrict__ out)
{
    __shared__ __align__(16) char ring[65536];
    const int tid  = threadIdx.x;
    const int wv   = tid >> 6;    // 0 = compute wave, 1 = xp producer wave
    const int lane = tid & 63;
    const int col  = lane & 15;
    const int kg   = lane >> 4;
    const int bb0  = blockIdx.x * BT;
    char* lring = ring + (lane << 4);

    if (wv == 0) {
        // ================= COMPUTE WAVE: full h-chain in registers =========
        // whh[tt][kk]: A-frag rows 16tt..+15, phys k 32kk..+31, cols permuted:
        // slot j holds W_hh[16tt+col][32kk + 16*(j>>2) + 4kg + (j&3)]
        bf16x8 whh[8][4];
        #pragma unroll
        for (int tt = 0; tt < 8; ++tt) {
            #pragma unroll
            for (int kk = 0; kk < 4; ++kk) {
                const float* pw = W_hh + (16 * tt + col) * NHID + 32 * kk + 4 * kg;
                f32x4 c0 = *(const f32x4*)(pw);        // j = 0..3
                f32x4 c1 = *(const f32x4*)(pw + 16);   // j = 4..7
                union { bf16x8 v; unsigned u[4]; } fr;
                fr.u[0] = cvt_pk(c0[0], c0[1]); fr.u[1] = cvt_pk(c0[2], c0[3]);
                fr.u[2] = cvt_pk(c1[0], c1[1]); fr.u[3] = cvt_pk(c1[2], c1[3]);
                whh[tt][kk] = fr.v;
            }
        }
        __syncthreads();   // producer has written xp(0..3) into slots 0..3

        f32x4 xpbuf[8];
        #pragma unroll
        for (int tt = 0; tt < 8; ++tt)
            xpbuf[tt] = *(const f32x4*)(lring + (tt << 10));   // xp(0), slot 0

        bf16x8 B[4];
        {
            bf16x8 zb = {0, 0, 0, 0, 0, 0, 0, 0};
            B[0] = zb; B[1] = zb; B[2] = zb; B[3] = zb;        // h(0) = 0
        }

        for (int m = 0; m < 256; ++m) {
            #pragma unroll
            for (int e = 0; e < 4; ++e) {
                const int t = 4 * m + e;
                f32x4 acc[8];
                #pragma unroll
                for (int tt = 0; tt < 8; ++tt) acc[tt] = xpbuf[tt];
                // 32 MFMAs, kk-outer for dependency spacing (8 indep chains)
                #pragma unroll
                for (int kk = 0; kk < 4; ++kk) {
                    acc[0] = MFMA(whh[0][kk], B[kk], acc[0], 0, 0, 0);
                    acc[1] = MFMA(whh[1][kk], B[kk], acc[1], 0, 0, 0);
                    acc[2] = MFMA(whh[2][kk], B[kk], acc[2], 0, 0, 0);
                    acc[3] = MFMA(whh[3][kk], B[kk], acc[3], 0, 0, 0);
                }
                #pragma unroll
                for (int kk = 0; kk < 4; ++kk) {
                    acc[4] = MFMA(whh[4][kk], B[kk], acc[4], 0, 0, 0);
                    acc[5] = MFMA(whh[5][kk], B[kk], acc[5], 0, 0, 0);
                    acc[6] = MFMA(whh[6][kk], B[kk], acc[6], 0, 0, 0);
                    acc[7] = MFMA(whh[7][kk], B[kk], acc[7], 0, 0, 0);
                }
                // prefetch xp(t+1) (same interval only); waited at next acc init
                if (e != 3) {
                    const int slot = (t + 1) & 7;
                    #pragma unroll
                    for (int tt = 0; tt < 8; ++tt)
                        xpbuf[tt] = *(const f32x4*)(lring + (slot << 13) + (tt << 10));
                }
                // tanh overlaps the matrix-pipe backlog
                #pragma unroll
                for (int tt = 0; tt < 8; ++tt) {
                    #pragma unroll
                    for (int i = 0; i < 4; ++i) acc[tt][i] = tanh_fast(acc[tt][i]);
                }
                if (t == S_LEN - 1) {
                    #pragma unroll
                    for (int tt = 0; tt < 8; ++tt)
                        *(f32x4*)(out + ((size_t)bb0 + col) * NHID + 16 * tt + 4 * kg)
                            = acc[tt];
                } else {
                    // B-frags for t+1: same-lane repack (the permuted-k payoff)
                    #pragma unroll
                    for (int kk = 0; kk < 4; ++kk) {
                        union { bf16x8 v; unsigned u[4]; } fb;
                        fb.u[0] = cvt_pk(acc[2 * kk][0],     acc[2 * kk][1]);
                        fb.u[1] = cvt_pk(acc[2 * kk][2],     acc[2 * kk][3]);
                        fb.u[2] = cvt_pk(acc[2 * kk + 1][0], acc[2 * kk + 1][1]);
                        fb.u[3] = cvt_pk(acc[2 * kk + 1][2], acc[2 * kk + 1][3]);
                        B[kk] = fb.v;
                    }
                }
            }
            lds_barrier();     // once per 4 steps: compute arrives last, ~free
            if (m < 255) {
                const int slot = (4 * m + 4) & 7;
                #pragma unroll
                for (int tt = 0; tt < 8; ++tt)
                    xpbuf[tt] = *(const f32x4*)(lring + (slot << 13) + (tt << 10));
            }
        }
    } else {
        // ================= PRODUCER WAVE: xp(t) = b + W_ih @ x_t ===========
        bf16x8 wih[8][2];   // natural layout (x side unpermuted)
        #pragma unroll
        for (int tt = 0; tt < 8; ++tt) {
            #pragma unroll
            for (int kk = 0; kk < 2; ++kk) {
                const float* q = W_ih + (16 * tt + col) * NIN + 32 * kk + 8 * kg;
                f32x4 c0 = *(const f32x4*)(q);
                f32x4 c1 = *(const f32x4*)(q + 4);
                union { bf16x8 v; unsigned u[4]; } fr;
                fr.u[0] = cvt_pk(c0[0], c0[1]); fr.u[1] = cvt_pk(c0[2], c0[3]);
                fr.u[2] = cvt_pk(c1[0], c1[1]); fr.u[3] = cvt_pk(c1[2], c1[3]);
                wih[tt][kk] = fr.v;
            }
        }
        f32x4 biasv[8];
        #pragma unroll
        for (int tt = 0; tt < 8; ++tt) {
            f32x4 bi = *(const f32x4*)(b_ih + 16 * tt + 4 * kg);
            f32x4 bh = *(const f32x4*)(b_hh + 16 * tt + 4 * kg);
            biasv[tt] = bi + bh;
        }
        const float* xlane = x + ((size_t)bb0 + col) * NIN + kg * 8;

        auto loadS = [&](f32x4* s, int t) {
            if (t < S_LEN) {
                const float* p = xlane + (size_t)t * (BATCH * NIN);
                s[0] = *(const f32x4*)(p);
                s[1] = *(const f32x4*)(p + 4);
                s[2] = *(const f32x4*)(p + 32);
                s[3] = *(const f32x4*)(p + 36);
            }
        };
        auto produce = [&](const f32x4* s, int q) {
            union { bf16x8 v; unsigned u[4]; } xa, xb;
            xa.u[0] = cvt_pk(s[0][0], s[0][1]); xa.u[1] = cvt_pk(s[0][2], s[0][3]);
            xa.u[2] = cvt_pk(s[1][0], s[1][1]); xa.u[3] = cvt_pk(s[1][2], s[1][3]);
            xb.u[0] = cvt_pk(s[2][0], s[2][1]); xb.u[1] = cvt_pk(s[2][2], s[2][3]);
            xb.u[2] = cvt_pk(s[3][0], s[3][1]); xb.u[3] = cvt_pk(s[3][2], s[3][3]);
            char* dst = lring + ((q & 7) << 13);
            #pragma unroll
            for (int tt = 0; tt < 8; ++tt) {
                f32x4 a = biasv[tt];
                a = MFMA(wih[tt][0], xa.v, a, 0, 0, 0);
                a = MFMA(wih[tt][1], xb.v, a, 0, 0, 0);
                *(f32x4*)(dst + (tt << 10)) = a;   // ds_write_b128, lane-contig
            }
        };

        // prologue: xp(0..3) -> slots 0..3; prime stages with x(4..7)
        {
            f32x4 tmp[4];
            for (int q = 0; q < 4; ++q) { loadS(tmp, q); produce(tmp, q); }
        }
        f32x4 S[4][4];
        #pragma unroll
        for (int e = 0; e < 4; ++e) loadS(S[e], 4 + e);
        __syncthreads();

        // interval m: write xp(4m+4 .. 4m+7) (slots disjoint from the ones the
        // compute wave reads this interval); refill stage with x(q+4)
        for (int m = 0; m < 256; ++m) {
            #pragma unroll
            for (int e = 0; e < 4; ++e) {
                const int q = 4 * m + 4 + e;
                if (q < S_LEN) {
                    produce(S[e], q);
                    loadS(S[e], q + 4);
                }
            }
            lds_barrier();
        }
    }
}

extern "C" void kernel_launch(void* const* d_in, const int* in_sizes, int n_in,
                              void* d_out, int out_size, void* d_ws, size_t ws_size,
                              hipStream_t stream) {
    const float* x    = (const float*)d_in[0];
    const float* W_ih = (const float*)d_in[1];
    const float* b_ih = (const float*)d_in[2];
    const float* W_hh = (const float*)d_in[3];
    const float* b_hh = (const float*)d_in[4];
    float* out = (float*)d_out;

    dim3 grid(BATCH / BT);
    dim3 block(128);
    rnn_kernel<<<grid, block, 0, stream>>>(x, W_ih, b_ih, W_hh, b_hh, out);
}

// Round 7
// 527.894 us; speedup vs baseline: 1.7018x; 1.4256x over previous
//
#include <hip/hip_runtime.h>

#define S_LEN 1024
#define BATCH 4096
#define NIN 64
#define NHID 128
#define BT 16      // batch rows per block (one h-chain per block)

typedef __attribute__((ext_vector_type(8))) short bf16x8;
typedef __attribute__((ext_vector_type(4))) float f32x4;

// LDS map:
//   [0, 32768)      xp ring, 4 slots x 8KB: slot s at s<<13, tt at tt<<10, lane<<4
//   [32768, 40960)  B exchange, 2 bufs x 4KB: buf b at b<<12, kk at kk<<10, lane<<4
#define XP_BASE 0
#define BX_BASE 32768

__device__ __forceinline__ unsigned cvt_pk(float lo, float hi) {
    unsigned r;
    asm("v_cvt_pk_bf16_f32 %0, %1, %2" : "=v"(r) : "v"(lo), "v"(hi));
    return r;
}
__device__ __forceinline__ float tanh_fast(float z) {
    float u = __builtin_amdgcn_exp2f(z * 2.885390081777927f);
    return (u - 1.0f) * __builtin_amdgcn_rcpf(u + 1.0f);
}
// barrier without vmcnt drain (producers' global x loads stay in flight)
__device__ __forceinline__ void lds_barrier() {
    asm volatile("s_waitcnt lgkmcnt(0)\n\ts_barrier" ::: "memory");
}

#define MFMA __builtin_amdgcn_mfma_f32_16x16x32_bf16

// Permuted-k (verified R6): B-slot (kk,kg,j) carries logical hidden index
// m = 32kk + 16*(j>>2) + 4kg + (j&3), so B[kk] = cvt_pk repack of the SAME
// LANE's acc[2kk],acc[2kk+1]. Split across waves: wave0 owns tt 0..3 -> its
// accs produce exactly B[0],B[1]; wave1 (tt 4..7) produces B[2],B[3]. Own
// half stays in registers; only the partner half crosses LDS.

__global__ __launch_bounds__(256, 1)
void rnn_kernel(const float* __restrict__ x,
                const float* __restrict__ W_ih,
                const float* __restrict__ b_ih,
                const float* __restrict__ W_hh,
                const float* __restrict__ b_hh,
                float* __restrict__ out)
{
    __shared__ __align__(16) char lds[40960];
    const int tid  = threadIdx.x;
    const int wv   = tid >> 6;    // 0,1 compute halves; 2,3 xp producers
    const int lane = tid & 63;
    const int col  = lane & 15;
    const int kg   = lane >> 4;
    const int bb0  = blockIdx.x * BT;

    // zero B exchange (h_0 = 0): 8192 B = 2048 ints
    for (int i = tid; i < 2048; i += 256) ((int*)(lds + BX_BASE))[i] = 0;

    if (wv < 2) {
        // ============ COMPUTE WAVE (half of hidden dims) ============
        const int half = wv;
        const int ttb  = 4 * half;        // tt = ttb..ttb+3
        const int okk  = 2 * half;        // own B slots
        const int pkk  = 2 - 2 * half;    // partner B slots
        // whO[lt][i]: frag (tt=ttb+lt, kk=okk+i); whP: kk=pkk+i (col-permuted)
        bf16x8 whO[4][2], whP[4][2];
        #pragma unroll
        for (int lt = 0; lt < 4; ++lt) {
            const float* rowp = W_hh + (16 * (ttb + lt) + col) * NHID + 4 * kg;
            #pragma unroll
            for (int i = 0; i < 2; ++i) {
                {
                    const float* pw = rowp + 32 * (okk + i);
                    f32x4 c0 = *(const f32x4*)(pw);
                    f32x4 c1 = *(const f32x4*)(pw + 16);
                    union { bf16x8 v; unsigned u[4]; } fr;
                    fr.u[0] = cvt_pk(c0[0], c0[1]); fr.u[1] = cvt_pk(c0[2], c0[3]);
                    fr.u[2] = cvt_pk(c1[0], c1[1]); fr.u[3] = cvt_pk(c1[2], c1[3]);
                    whO[lt][i] = fr.v;
                }
                {
                    const float* pw = rowp + 32 * (pkk + i);
                    f32x4 c0 = *(const f32x4*)(pw);
                    f32x4 c1 = *(const f32x4*)(pw + 16);
                    union { bf16x8 v; unsigned u[4]; } fr;
                    fr.u[0] = cvt_pk(c0[0], c0[1]); fr.u[1] = cvt_pk(c0[2], c0[3]);
                    fr.u[2] = cvt_pk(c1[0], c1[1]); fr.u[3] = cvt_pk(c1[2], c1[3]);
                    whP[lt][i] = fr.v;
                }
            }
        }
        __syncthreads();   // producers wrote xp(0..2); B bufs zeroed

        char* lxp = lds + XP_BASE + ((ttb) << 10) + (lane << 4);
        char* lbx = lds + BX_BASE + (lane << 4);

        f32x4 xpA[4], xpB[4];
        #pragma unroll
        for (int lt = 0; lt < 4; ++lt)
            xpA[lt] = *(const f32x4*)(lxp + (lt << 10));   // xp(0), slot 0

        bf16x8 B0 = {0,0,0,0,0,0,0,0}, B1 = B0;            // own half of h(0)=0

        auto cstep = [&](int t, f32x4 (&xpc)[4], f32x4 (&xpn)[4]) {
            // partner B for this step (written by partner at t-1, buf t&1)
            const char* bp = lbx + ((t & 1) << 12);
            bf16x8 P0 = *(const bf16x8*)(bp + (pkk << 10));
            bf16x8 P1 = *(const bf16x8*)(bp + ((pkk + 1) << 10));

            f32x4 a0 = xpc[0], a1 = xpc[1], a2 = xpc[2], a3 = xpc[3];
            // own-half MFMAs first: partner-read latency hides under these
            a0 = MFMA(whO[0][0], B0, a0, 0, 0, 0);
            a1 = MFMA(whO[1][0], B0, a1, 0, 0, 0);
            a2 = MFMA(whO[2][0], B0, a2, 0, 0, 0);
            a3 = MFMA(whO[3][0], B0, a3, 0, 0, 0);
            a0 = MFMA(whO[0][1], B1, a0, 0, 0, 0);
            a1 = MFMA(whO[1][1], B1, a1, 0, 0, 0);
            a2 = MFMA(whO[2][1], B1, a2, 0, 0, 0);
            a3 = MFMA(whO[3][1], B1, a3, 0, 0, 0);
            a0 = MFMA(whP[0][0], P0, a0, 0, 0, 0);
            a1 = MFMA(whP[1][0], P0, a1, 0, 0, 0);
            a2 = MFMA(whP[2][0], P0, a2, 0, 0, 0);
            a3 = MFMA(whP[3][0], P0, a3, 0, 0, 0);
            a0 = MFMA(whP[0][1], P1, a0, 0, 0, 0);
            a1 = MFMA(whP[1][1], P1, a1, 0, 0, 0);
            a2 = MFMA(whP[2][1], P1, a2, 0, 0, 0);
            a3 = MFMA(whP[3][1], P1, a3, 0, 0, 0);

            // prefetch xp(t+1) (independent; overlaps MFMA/tanh)
            if (t + 1 < S_LEN) {
                const char* q = lxp + (((t + 1) & 3) << 13);
                #pragma unroll
                for (int lt = 0; lt < 4; ++lt)
                    xpn[lt] = *(const f32x4*)(q + (lt << 10));
            }

            #pragma unroll
            for (int i = 0; i < 4; ++i) a0[i] = tanh_fast(a0[i]);
            #pragma unroll
            for (int i = 0; i < 4; ++i) a1[i] = tanh_fast(a1[i]);
            #pragma unroll
            for (int i = 0; i < 4; ++i) a2[i] = tanh_fast(a2[i]);
            #pragma unroll
            for (int i = 0; i < 4; ++i) a3[i] = tanh_fast(a3[i]);

            if (t == S_LEN - 1) {
                float* ob = out + ((size_t)bb0 + col) * NHID + 16 * ttb + 4 * kg;
                *(f32x4*)(ob)      = a0;
                *(f32x4*)(ob + 16) = a1;
                *(f32x4*)(ob + 32) = a2;
                *(f32x4*)(ob + 48) = a3;
            } else {
                // repack own half for t+1 (same-lane, permuted-k payoff)
                union { bf16x8 v; unsigned u[4]; } f0, f1;
                f0.u[0] = cvt_pk(a0[0], a0[1]); f0.u[1] = cvt_pk(a0[2], a0[3]);
                f0.u[2] = cvt_pk(a1[0], a1[1]); f0.u[3] = cvt_pk(a1[2], a1[3]);
                f1.u[0] = cvt_pk(a2[0], a2[1]); f1.u[1] = cvt_pk(a2[2], a2[3]);
                f1.u[2] = cvt_pk(a3[0], a3[1]); f1.u[3] = cvt_pk(a3[2], a3[3]);
                B0 = f0.v; B1 = f1.v;
                char* bw = lbx + (((t + 1) & 1) << 12);
                *(bf16x8*)(bw + (okk << 10))       = B0;
                *(bf16x8*)(bw + ((okk + 1) << 10)) = B1;
            }
            lds_barrier();
        };

        for (int m = 0; m < S_LEN / 2; ++m) {
            cstep(2 * m,     xpA, xpB);
            cstep(2 * m + 1, xpB, xpA);
        }
    } else {
        // ============ PRODUCER WAVE: xp for half the hidden dims ============
        const int ph  = wv - 2;
        const int ttb = 4 * ph;
        bf16x8 wih[4][2];
        f32x4 bias[4];
        #pragma unroll
        for (int lt = 0; lt < 4; ++lt) {
            #pragma unroll
            for (int kk = 0; kk < 2; ++kk) {
                const float* q = W_ih + (16 * (ttb + lt) + col) * NIN + 32 * kk + 8 * kg;
                f32x4 c0 = *(const f32x4*)(q);
                f32x4 c1 = *(const f32x4*)(q + 4);
                union { bf16x8 v; unsigned u[4]; } fr;
                fr.u[0] = cvt_pk(c0[0], c0[1]); fr.u[1] = cvt_pk(c0[2], c0[3]);
                fr.u[2] = cvt_pk(c1[0], c1[1]); fr.u[3] = cvt_pk(c1[2], c1[3]);
                wih[lt][kk] = fr.v;
            }
            f32x4 bi = *(const f32x4*)(b_ih + 16 * (ttb + lt) + 4 * kg);
            f32x4 bh = *(const f32x4*)(b_hh + 16 * (ttb + lt) + 4 * kg);
            bias[lt] = bi + bh;
        }
        const float* xlane = x + ((size_t)bb0 + col) * NIN + kg * 8;
        char* lxp = lds + XP_BASE + (ttb << 10) + (lane << 4);

        auto loadS = [&](f32x4* s, int t) {
            if (t < S_LEN) {
                const float* p = xlane + (size_t)t * (BATCH * NIN);
                s[0] = *(const f32x4*)(p);
                s[1] = *(const f32x4*)(p + 4);
                s[2] = *(const f32x4*)(p + 32);
                s[3] = *(const f32x4*)(p + 36);
            }
        };
        auto produce = [&](const f32x4* s, int q) {
            union { bf16x8 v; unsigned u[4]; } xa, xb;
            xa.u[0] = cvt_pk(s[0][0], s[0][1]); xa.u[1] = cvt_pk(s[0][2], s[0][3]);
            xa.u[2] = cvt_pk(s[1][0], s[1][1]); xa.u[3] = cvt_pk(s[1][2], s[1][3]);
            xb.u[0] = cvt_pk(s[2][0], s[2][1]); xb.u[1] = cvt_pk(s[2][2], s[2][3]);
            xb.u[2] = cvt_pk(s[3][0], s[3][1]); xb.u[3] = cvt_pk(s[3][2], s[3][3]);
            char* dst = lxp + ((q & 3) << 13);
            #pragma unroll
            for (int lt = 0; lt < 4; ++lt) {
                f32x4 a = bias[lt];
                a = MFMA(wih[lt][0], xa.v, a, 0, 0, 0);
                a = MFMA(wih[lt][1], xb.v, a, 0, 0, 0);
                *(f32x4*)(dst + (lt << 10)) = a;
            }
        };

        // prologue: xp(0..2) -> slots 0..2; prime stages with x(3..6)
        {
            f32x4 T[4];
            for (int q = 0; q < 3; ++q) { loadS(T, q); produce(T, q); }
        }
        f32x4 S[4][4];
        #pragma unroll
        for (int e = 0; e < 4; ++e) loadS(S[e], 3 + e);
        __syncthreads();

        for (int m = 0; m < S_LEN / 4; ++m) {
            #pragma unroll
            for (int e = 0; e < 4; ++e) {
                const int t = 4 * m + e;
                if (t + 3 < S_LEN) produce(S[e], t + 3);
                loadS(S[e], t + 7);
                lds_barrier();
            }
        }
    }
}

extern "C" void kernel_launch(void* const* d_in, const int* in_sizes, int n_in,
                              void* d_out, int out_size, void* d_ws, size_t ws_size,
                              hipStream_t stream) {
    const float* x    = (const float*)d_in[0];
    const float* W_ih = (const float*)d_in[1];
    const float* b_ih = (const float*)d_in[2];
    const float* W_hh = (const float*)d_in[3];
    const float* b_hh = (const float*)d_in[4];
    float* out = (float*)d_out;

    dim3 grid(BATCH / BT);
    dim3 block(256);
    rnn_kernel<<<grid, block, 0, stream>>>(x, W_ih, b_ih, W_hh, b_hh, out);
}

// Round 9
// 455.534 us; speedup vs baseline: 1.9721x; 1.1588x over previous
//
#include <hip/hip_runtime.h>

#define S_LEN 1024
#define BATCH 4096
#define NIN 64
#define NHID 128
#define BT 16      // batch rows per block (one h-chain per block)

typedef __attribute__((ext_vector_type(8))) short bf16x8;
typedef __attribute__((ext_vector_type(4))) float f32x4;

__device__ __forceinline__ unsigned cvt_pk(float lo, float hi) {
    unsigned r;
    asm("v_cvt_pk_bf16_f32 %0, %1, %2" : "=v"(r) : "v"(lo), "v"(hi));
    return r;
}
__device__ __forceinline__ float tanh_fast(float z) {
    float u = __builtin_amdgcn_exp2f(z * 2.885390081777927f);
    return (u - 1.0f) * __builtin_amdgcn_rcpf(u + 1.0f);
}
// barrier without vmcnt drain (x prefetch loads stay in flight);
// sched_barrier: rule-#18 insurance against hoisting across the asm.
__device__ __forceinline__ void lds_barrier() {
    asm volatile("s_waitcnt lgkmcnt(0)\n\ts_barrier" ::: "memory");
    __builtin_amdgcn_sched_barrier(0);
}

#define MFMA __builtin_amdgcn_mfma_f32_16x16x32_bf16

// Permuted-k (verified R6/R7): B-slot (kk,kg,j) carries logical hidden index
// m = 32kk + 16*(j>>2) + 4kg + (j&3)  =>  B[kk] = same-lane cvt_pk repack of
// acc[tt=2kk], acc[tt=2kk+1]. Wave OWN (=wv) owns tt {2*OWN, 2*OWN+1}: its
// accs produce exactly B[OWN] (kept in registers); 3 partner slots cross LDS.
// LDS: B exchange only, 2 bufs x 4KB: buf b at b<<12, slot kk at kk<<10, lane<<4.

__global__ __launch_bounds__(256, 1)
void rnn_kernel(const float* __restrict__ x,
                const float* __restrict__ W_ih,
                const float* __restrict__ b_ih,
                const float* __restrict__ W_hh,
                const float* __restrict__ b_hh,
                float* __restrict__ out)
{
    __shared__ __align__(16) char lds[8192];
    const int tid  = threadIdx.x;
    const int wv   = tid >> 6;        // 0..3 — one wave per SIMD, all same code
    const int lane = tid & 63;
    const int col  = lane & 15;
    const int kg   = lane >> 4;
    const int bb0  = blockIdx.x * BT;

    // zero B exchange (h_0 = 0)
    for (int i = tid; i < 2048; i += 256) ((int*)lds)[i] = 0;

    const int OWN = wv;               // runtime-uniform; used only in ADDRESSES
    char* lbx = lds + (lane << 4);
    char*       wp  = lbx + (OWN << 10);
    const char* rp1 = lbx + ((((OWN + 1) & 3)) << 10);
    const char* rp2 = lbx + ((((OWN + 2) & 3)) << 10);
    const char* rp3 = lbx + ((((OWN + 3) & 3)) << 10);

    // ---- persistent weights for tt0 = 2*OWN, tt1 = 2*OWN+1
    // whh0/whh1[q]: W_hh column-slice kk = (OWN+q)&3 (register index q: STATIC)
    bf16x8 whh0[4], whh1[4];
    const int tt0 = 2 * OWN, tt1 = tt0 + 1;
    #pragma unroll
    for (int q = 0; q < 4; ++q) {
        const int kkq = (OWN + q) & 3;                 // runtime-uniform addr
        {
            const float* pw = W_hh + (16 * tt0 + col) * NHID + 32 * kkq + 4 * kg;
            f32x4 c0 = *(const f32x4*)(pw);            // j = 0..3
            f32x4 c1 = *(const f32x4*)(pw + 16);       // j = 4..7
            union { bf16x8 v; unsigned u[4]; } fr;
            fr.u[0] = cvt_pk(c0[0], c0[1]); fr.u[1] = cvt_pk(c0[2], c0[3]);
            fr.u[2] = cvt_pk(c1[0], c1[1]); fr.u[3] = cvt_pk(c1[2], c1[3]);
            whh0[q] = fr.v;
        }
        {
            const float* pw = W_hh + (16 * tt1 + col) * NHID + 32 * kkq + 4 * kg;
            f32x4 c0 = *(const f32x4*)(pw);
            f32x4 c1 = *(const f32x4*)(pw + 16);
            union { bf16x8 v; unsigned u[4]; } fr;
            fr.u[0] = cvt_pk(c0[0], c0[1]); fr.u[1] = cvt_pk(c0[2], c0[3]);
            fr.u[2] = cvt_pk(c1[0], c1[1]); fr.u[3] = cvt_pk(c1[2], c1[3]);
            whh1[q] = fr.v;
        }
    }
    bf16x8 wihA0, wihB0, wihA1, wihB1;   // [lt][kk]: A=kk0, B=kk1 (natural k)
    {
        const float* q0 = W_ih + (16 * tt0 + col) * NIN + 8 * kg;
        const float* q1 = W_ih + (16 * tt1 + col) * NIN + 8 * kg;
        union { bf16x8 v; unsigned u[4]; } fr;
        f32x4 c0, c1;
        c0 = *(const f32x4*)(q0);      c1 = *(const f32x4*)(q0 + 4);
        fr.u[0] = cvt_pk(c0[0], c0[1]); fr.u[1] = cvt_pk(c0[2], c0[3]);
        fr.u[2] = cvt_pk(c1[0], c1[1]); fr.u[3] = cvt_pk(c1[2], c1[3]);
        wihA0 = fr.v;
        c0 = *(const f32x4*)(q0 + 32); c1 = *(const f32x4*)(q0 + 36);
        fr.u[0] = cvt_pk(c0[0], c0[1]); fr.u[1] = cvt_pk(c0[2], c0[3]);
        fr.u[2] = cvt_pk(c1[0], c1[1]); fr.u[3] = cvt_pk(c1[2], c1[3]);
        wihB0 = fr.v;
        c0 = *(const f32x4*)(q1);      c1 = *(const f32x4*)(q1 + 4);
        fr.u[0] = cvt_pk(c0[0], c0[1]); fr.u[1] = cvt_pk(c0[2], c0[3]);
        fr.u[2] = cvt_pk(c1[0], c1[1]); fr.u[3] = cvt_pk(c1[2], c1[3]);
        wihA1 = fr.v;
        c0 = *(const f32x4*)(q1 + 32); c1 = *(const f32x4*)(q1 + 36);
        fr.u[0] = cvt_pk(c0[0], c0[1]); fr.u[1] = cvt_pk(c0[2], c0[3]);
        fr.u[2] = cvt_pk(c1[0], c1[1]); fr.u[3] = cvt_pk(c1[2], c1[3]);
        wihB1 = fr.v;
    }
    f32x4 bias0, bias1;
    {
        f32x4 bi = *(const f32x4*)(b_ih + 16 * tt0 + 4 * kg);
        f32x4 bh = *(const f32x4*)(b_hh + 16 * tt0 + 4 * kg);
        bias0 = bi + bh;
        bi = *(const f32x4*)(b_ih + 16 * tt1 + 4 * kg);
        bh = *(const f32x4*)(b_hh + 16 * tt1 + 4 * kg);
        bias1 = bi + bh;
    }

    const float* xlane = x + ((size_t)bb0 + col) * NIN + kg * 8;

    auto loadStage = [&](f32x4& v0, f32x4& v1, f32x4& v2, f32x4& v3, int t) {
        if (t < S_LEN) {
            const float* p = xlane + (size_t)t * (BATCH * NIN);
            v0 = *(const f32x4*)(p);      v1 = *(const f32x4*)(p + 4);
            v2 = *(const f32x4*)(p + 32); v3 = *(const f32x4*)(p + 36);
        }
    };
    auto computeXP = [&](const f32x4& v0, const f32x4& v1,
                         const f32x4& v2, const f32x4& v3,
                         f32x4& o0, f32x4& o1) {
        union { bf16x8 v; unsigned u[4]; } xa, xb;
        xa.u[0] = cvt_pk(v0[0], v0[1]); xa.u[1] = cvt_pk(v0[2], v0[3]);
        xa.u[2] = cvt_pk(v1[0], v1[1]); xa.u[3] = cvt_pk(v1[2], v1[3]);
        xb.u[0] = cvt_pk(v2[0], v2[1]); xb.u[1] = cvt_pk(v2[2], v2[3]);
        xb.u[2] = cvt_pk(v3[0], v3[1]); xb.u[3] = cvt_pk(v3[2], v3[3]);
        f32x4 p0 = bias0, p1 = bias1;
        p0 = MFMA(wihA0, xa.v, p0, 0, 0, 0);
        p1 = MFMA(wihA1, xa.v, p1, 0, 0, 0);
        p0 = MFMA(wihB0, xb.v, p0, 0, 0, 0);
        p1 = MFMA(wihB1, xb.v, p1, 0, 0, 0);
        o0 = p0; o1 = p1;
    };

    // ---- prologue: stages <- x(0..3); xp(0); refill stage0 <- x(4)
    f32x4 S00, S01, S02, S03, S10, S11, S12, S13;
    f32x4 S20, S21, S22, S23, S30, S31, S32, S33;
    loadStage(S00, S01, S02, S03, 0);
    loadStage(S10, S11, S12, S13, 1);
    loadStage(S20, S21, S22, S23, 2);
    loadStage(S30, S31, S32, S33, 3);
    f32x4 xc0, xc1, xn0, xn1;
    computeXP(S00, S01, S02, S03, xc0, xc1);
    loadStage(S00, S01, S02, S03, 4);
    bf16x8 Bo = {0, 0, 0, 0, 0, 0, 0, 0};       // own slice of h(0) = 0
    __syncthreads();                            // B-zeros visible

    auto cstep = [&](int t, f32x4& s0, f32x4& s1, f32x4& s2, f32x4& s3,
                     const f32x4& c0, const f32x4& c1,
                     f32x4& n0, f32x4& n1, bool last) {
        // partner B reads first; latency hides under own-MFMA + xp block
        const int rb = (t & 1) << 12;
        bf16x8 P1 = *(const bf16x8*)(rp1 + rb);
        bf16x8 P2 = *(const bf16x8*)(rp2 + rb);
        bf16x8 P3 = *(const bf16x8*)(rp3 + rb);

        f32x4 a0 = c0, a1 = c1;
        a0 = MFMA(whh0[0], Bo, a0, 0, 0, 0);
        a1 = MFMA(whh1[0], Bo, a1, 0, 0, 0);

        computeXP(s0, s1, s2, s3, n0, n1);   // xp(t+1): independent issue
        loadStage(s0, s1, s2, s3, t + 5);    // refill (consumed at t+4)

        a0 = MFMA(whh0[1], P1, a0, 0, 0, 0);
        a1 = MFMA(whh1[1], P1, a1, 0, 0, 0);
        a0 = MFMA(whh0[2], P2, a0, 0, 0, 0);
        a1 = MFMA(whh1[2], P2, a1, 0, 0, 0);
        a0 = MFMA(whh0[3], P3, a0, 0, 0, 0);
        a1 = MFMA(whh1[3], P3, a1, 0, 0, 0);

        #pragma unroll
        for (int i = 0; i < 4; ++i) a0[i] = tanh_fast(a0[i]);
        #pragma unroll
        for (int i = 0; i < 4; ++i) a1[i] = tanh_fast(a1[i]);

        if (last) {
            float* ob = out + ((size_t)bb0 + col) * NHID + 32 * OWN + 4 * kg;
            *(f32x4*)(ob)      = a0;
            *(f32x4*)(ob + 16) = a1;
        } else {
            union { bf16x8 v; unsigned u[4]; } fb;
            fb.u[0] = cvt_pk(a0[0], a0[1]); fb.u[1] = cvt_pk(a0[2], a0[3]);
            fb.u[2] = cvt_pk(a1[0], a1[1]); fb.u[3] = cvt_pk(a1[2], a1[3]);
            Bo = fb.v;
            *(bf16x8*)(wp + (((t + 1) & 1) << 12)) = Bo;
        }
        lds_barrier();
    };

    for (int m = 0; m < 255; ++m) {
        const int t = 4 * m;
        cstep(t + 0, S10, S11, S12, S13, xc0, xc1, xn0, xn1, false);
        cstep(t + 1, S20, S21, S22, S23, xn0, xn1, xc0, xc1, false);
        cstep(t + 2, S30, S31, S32, S33, xc0, xc1, xn0, xn1, false);
        cstep(t + 3, S00, S01, S02, S03, xn0, xn1, xc0, xc1, false);
    }
    cstep(1020, S10, S11, S12, S13, xc0, xc1, xn0, xn1, false);
    cstep(1021, S20, S21, S22, S23, xn0, xn1, xc0, xc1, false);
    cstep(1022, S30, S31, S32, S33, xc0, xc1, xn0, xn1, false);
    cstep(1023, S00, S01, S02, S03, xn0, xn1, xc0, xc1, true);
}

extern "C" void kernel_launch(void* const* d_in, const int* in_sizes, int n_in,
                              void* d_out, int out_size, void* d_ws, size_t ws_size,
                              hipStream_t stream) {
    const float* x    = (const float*)d_in[0];
    const float* W_ih = (const float*)d_in[1];
    const float* b_ih = (const float*)d_in[2];
    const float* W_hh = (const float*)d_in[3];
    const float* b_hh = (const float*)d_in[4];
    float* out = (float*)d_out;

    dim3 grid(BATCH / BT);
    dim3 block(256);
    rnn_kernel<<<grid, block, 0, stream>>>(x, W_ih, b_ih, W_hh, b_hh, out);
}